// Round 7
// baseline (507.602 us; speedup 1.0000x reference)
//
#include <hip/hip_runtime.h>
#include <hip/hip_bf16.h>

typedef __hip_bfloat16 bf16;
typedef __attribute__((ext_vector_type(8))) short short8;
typedef __attribute__((ext_vector_type(4))) float f32x4;
typedef __attribute__((ext_vector_type(4))) unsigned short u16x4;

#define DMODEL 1280
#define DFFN   5120
#define BATCH  4
#define SEQ    1024
#define NHEAD  20
#define HDIM   64
#define NROWS  (BATCH * SEQ)   // 4096

// async global->LDS, 16B per lane (used by flash_attn K staging)
#define GLDS(g, l) __builtin_amdgcn_global_load_lds(                            \
    (const __attribute__((address_space(1))) void*)(g),                         \
    (__attribute__((address_space(3))) void*)(l), 16, 0, 0)

// raw barrier: lgkmcnt(0) only, leaves global loads in flight (m139 pattern)
#define LGKM_BARRIER() do {                                                     \
    __builtin_amdgcn_s_waitcnt(0xC07F); /* vmcnt=63, expcnt=7, lgkmcnt=0 */     \
    __builtin_amdgcn_s_barrier(); } while (0)

// ---------------------------------------------------------------------------
// Transpose + fp32->bf16 convert:  in [K,N] fp32  ->  out [N,K] bf16
// ---------------------------------------------------------------------------
__global__ __launch_bounds__(256) void transpose_cvt(
    const float* __restrict__ in, bf16* __restrict__ out, int K, int N)
{
    __shared__ float tile[32][33];
    const int n0 = blockIdx.x * 32;
    const int k0 = blockIdx.y * 32;
    const int tx = threadIdx.x;   // 0..31
    const int ty = threadIdx.y;   // 0..7
    for (int i = 0; i < 32; i += 8)
        tile[ty + i][tx] = in[(size_t)(k0 + ty + i) * N + (n0 + tx)];
    __syncthreads();
    for (int i = 0; i < 32; i += 8)
        out[(size_t)(n0 + ty + i) * K + (k0 + tx)] = __float2bfloat16(tile[tx][ty + i]);
}

// 4 square DMODELxDMODEL transposes in one dispatch (blockIdx.z selects matrix)
__global__ __launch_bounds__(256) void transpose_cvt4(
    const float* __restrict__ s0, const float* __restrict__ s1,
    const float* __restrict__ s2, const float* __restrict__ s3,
    bf16* __restrict__ d0, bf16* __restrict__ d1,
    bf16* __restrict__ d2, bf16* __restrict__ d3)
{
    __shared__ float tile[32][33];
    const float* in;
    bf16* out;
    switch (blockIdx.z) {
        case 0: in = s0; out = d0; break;
        case 1: in = s1; out = d1; break;
        case 2: in = s2; out = d2; break;
        default: in = s3; out = d3; break;
    }
    const int n0 = blockIdx.x * 32;
    const int k0 = blockIdx.y * 32;
    const int tx = threadIdx.x;
    const int ty = threadIdx.y;
    for (int i = 0; i < 32; i += 8)
        tile[ty + i][tx] = in[(size_t)(k0 + ty + i) * DMODEL + (n0 + tx)];
    __syncthreads();
    for (int i = 0; i < 32; i += 8)
        out[(size_t)(n0 + ty + i) * DMODEL + (k0 + tx)] = __float2bfloat16(tile[tx][ty + i]);
}

// pack 3 bias vectors into one [3*DMODEL] buffer
__global__ __launch_bounds__(256) void pack_bias3(
    const float* __restrict__ a, const float* __restrict__ b,
    const float* __restrict__ c, float* __restrict__ o)
{
    const int i = blockIdx.x * 256 + threadIdx.x;
    if (i < DMODEL) {
        o[i] = a[i];
        o[DMODEL + i] = b[i];
        o[2 * DMODEL + i] = c[i];
    }
}

// ---------------------------------------------------------------------------
// LayerNorm over last dim (1280), one block (256 thr) per row, bf16 out
// ---------------------------------------------------------------------------
__global__ __launch_bounds__(256) void ln_bf16(
    const float* __restrict__ x, const float* __restrict__ sc,
    const float* __restrict__ of, bf16* __restrict__ out)
{
    const int row = blockIdx.x;
    const float* xr = x + (size_t)row * DMODEL;
    float v[5];
    float s = 0.f, s2 = 0.f;
    for (int i = 0; i < 5; ++i) {
        v[i] = xr[threadIdx.x + i * 256];
        s += v[i];
        s2 += v[i] * v[i];
    }
    for (int off = 1; off < 64; off <<= 1) {
        s  += __shfl_xor(s, off);
        s2 += __shfl_xor(s2, off);
    }
    __shared__ float red[2][4];
    const int wid = threadIdx.x >> 6;
    if ((threadIdx.x & 63) == 0) { red[0][wid] = s; red[1][wid] = s2; }
    __syncthreads();
    s  = red[0][0] + red[0][1] + red[0][2] + red[0][3];
    s2 = red[1][0] + red[1][1] + red[1][2] + red[1][3];
    const float mean = s * (1.0f / DMODEL);
    const float var  = s2 * (1.0f / DMODEL) - mean * mean;
    const float rstd = rsqrtf(var + 1e-5f);
    for (int i = 0; i < 5; ++i) {
        const int c = threadIdx.x + i * 256;
        const float y = (v[i] - mean) * rstd * sc[c] + of[c];
        out[(size_t)row * DMODEL + c] = __float2bfloat16(y);
    }
}

// ---------------------------------------------------------------------------
// Fused: x1 = P0 + P1 + bias + res;  h2 = LayerNorm(x1)*sc + of  (bf16)
// ---------------------------------------------------------------------------
__global__ __launch_bounds__(256) void reduce2_ln(
    const float* __restrict__ P, const float* __restrict__ bias,
    const float* __restrict__ res, float* __restrict__ x1,
    const float* __restrict__ sc, const float* __restrict__ of,
    bf16* __restrict__ h2)
{
    const int row = blockIdx.x;
    const size_t base = (size_t)row * DMODEL;
    const int MN = NROWS * DMODEL;
    float v[5];
    float s = 0.f, s2 = 0.f;
    for (int i = 0; i < 5; ++i) {
        const int c = threadIdx.x + i * 256;
        const float val = P[base + c] + P[MN + base + c] + bias[c] + res[base + c];
        v[i] = val;
        x1[base + c] = val;
        s += val;
        s2 += val * val;
    }
    for (int off = 1; off < 64; off <<= 1) {
        s  += __shfl_xor(s, off);
        s2 += __shfl_xor(s2, off);
    }
    __shared__ float red[2][4];
    const int wid = threadIdx.x >> 6;
    if ((threadIdx.x & 63) == 0) { red[0][wid] = s; red[1][wid] = s2; }
    __syncthreads();
    s  = red[0][0] + red[0][1] + red[0][2] + red[0][3];
    s2 = red[1][0] + red[1][1] + red[1][2] + red[1][3];
    const float mean = s * (1.0f / DMODEL);
    const float var  = s2 * (1.0f / DMODEL) - mean * mean;
    const float rstd = rsqrtf(var + 1e-5f);
    for (int i = 0; i < 5; ++i) {
        const int c = threadIdx.x + i * 256;
        const float y = (v[i] - mean) * rstd * sc[c] + of[c];
        h2[base + c] = __float2bfloat16(y);
    }
}

// ---------------------------------------------------------------------------
// bf16 MFMA GEMM v4: C = A[M,K] @ Bt[N,K]^T
// hipBLASLt-style K-loop: buffer_load -> VGPR (issued 1 full iter before
// first use) -> ds_write -> LDS dbuf; raw s_barrier waits lgkmcnt(0) ONLY,
// so global loads stay in flight ACROSS the barrier (no vmcnt(0) drain --
// the structural fix for the 22%-MfmaUtil plateau of rounds 4-6).
//  - swizzle key (row>>1)&3: 2 lanes/quad per phase on both ds_write and
//    ds_read_b128 (2-way aliasing = free per m136).
//  - m-tile = blockIdx.x fastest (XCD/L2 locality, round-3 win).
// EPI 0: bf16 out = acc + bias
// EPI 2: bf16 out = gelu_exact(acc + bias)
// EPI 3: f32 partial[z] = acc  (split-K via blockIdx.z)
// nIter = klen/32 must be EVEN (all our shapes: 40, 20, 80).
// ---------------------------------------------------------------------------
template <int EPI>
__global__ __launch_bounds__(256, 3) void gemm_bf16(
    const bf16* __restrict__ A, const bf16* __restrict__ Bt,
    const float* __restrict__ bias,
    bf16* __restrict__ Cb, float* __restrict__ Cf,
    int M, int N, int K, int klen)
{
    __shared__ bf16 As[2][128][32];   // 16 KB
    __shared__ bf16 Bs[2][128][32];   // 16 KB
    const int m0 = blockIdx.x * 128;
    const int n0 = blockIdx.y * 128;
    const int z  = blockIdx.z;
    const int kbeg = z * klen;

    const int tid  = threadIdx.x;
    const int lane = tid & 63;
    const int wid  = tid >> 6;
    const int wm   = (wid >> 1) * 64;
    const int wn   = (wid & 1) * 64;
    const int l15  = lane & 15;
    const int lq   = lane >> 4;

    f32x4 acc[4][4];
    for (int i = 0; i < 4; ++i)
        for (int j = 0; j < 4; ++j)
            acc[i][j] = (f32x4){0.f, 0.f, 0.f, 0.f};

    // staging map: thread -> tile row (t>>1), two 16B chunks ((t&1)*2 +{0,1})
    const int srow = tid >> 1;
    const int sc0  = (tid & 1) * 2;
    const int skey = (srow >> 1) & 3;
    const int sp0  = (sc0 ^ skey) * 8;         // physical elem offset chunk 0
    const int sp1  = ((sc0 + 1) ^ skey) * 8;   // physical elem offset chunk 1

    const bf16* aS = A  + (size_t)(m0 + srow) * K + kbeg + sc0 * 8;
    const bf16* bS = Bt + (size_t)(n0 + srow) * K + kbeg + sc0 * 8;

    uint4 a0c0, a0c1, b0c0, b0c1;   // reg set 0
    uint4 a1c0, a1c1, b1c0, b1c1;   // reg set 1

#define LOADSET0(k0) do {                                                       \
    a0c0 = *(const uint4*)(aS + (k0));  a0c1 = *(const uint4*)(aS + (k0) + 8);  \
    b0c0 = *(const uint4*)(bS + (k0));  b0c1 = *(const uint4*)(bS + (k0) + 8);  \
} while (0)
#define LOADSET1(k0) do {                                                       \
    a1c0 = *(const uint4*)(aS + (k0));  a1c1 = *(const uint4*)(aS + (k0) + 8);  \
    b1c0 = *(const uint4*)(bS + (k0));  b1c1 = *(const uint4*)(bS + (k0) + 8);  \
} while (0)
#define WRITESET0(buf) do {                                                     \
    *(uint4*)(&As[buf][srow][sp0]) = a0c0; *(uint4*)(&As[buf][srow][sp1]) = a0c1; \
    *(uint4*)(&Bs[buf][srow][sp0]) = b0c0; *(uint4*)(&Bs[buf][srow][sp1]) = b0c1; \
} while (0)
#define WRITESET1(buf) do {                                                     \
    *(uint4*)(&As[buf][srow][sp0]) = a1c0; *(uint4*)(&As[buf][srow][sp1]) = a1c1; \
    *(uint4*)(&Bs[buf][srow][sp0]) = b1c0; *(uint4*)(&Bs[buf][srow][sp1]) = b1c1; \
} while (0)

    const int ca = (lq ^ ((l15 >> 1) & 3)) * 8;   // frag chunk (2-way free)
#define COMPUTE(buf) do {                                                       \
    short8 af[4], bfr[4];                                                       \
    for (int mt = 0; mt < 4; ++mt)                                              \
        af[mt] = *(const short8*)(&As[buf][wm + mt * 16 + l15][ca]);            \
    for (int nt = 0; nt < 4; ++nt)                                              \
        bfr[nt] = *(const short8*)(&Bs[buf][wn + nt * 16 + l15][ca]);           \
    for (int mt = 0; mt < 4; ++mt)                                              \
        for (int nt = 0; nt < 4; ++nt)                                          \
            acc[mt][nt] = __builtin_amdgcn_mfma_f32_16x16x32_bf16(              \
                af[mt], bfr[nt], acc[mt][nt], 0, 0, 0);                         \
} while (0)

    const int nIter = klen / 32;   // even by construction
    LOADSET0(0);
    LOADSET1(32);
    WRITESET0(0);          // waits vmcnt for set0 only; set1 stays in flight
    LGKM_BARRIER();        // publish buf0

    for (int it = 0; it + 2 <= nIter; it += 2) {
        // even sub-iter: compute tile it (buf0); write T(it+1)->buf1
        if (it + 2 < nIter) LOADSET0((it + 2) * 32);
        WRITESET1(1);      // vmcnt wait leaves the just-issued loads in flight
        COMPUTE(0);
        LGKM_BARRIER();
        // odd sub-iter: compute tile it+1 (buf1); write T(it+2)->buf0
        if (it + 3 < nIter) LOADSET1((it + 3) * 32);
        if (it + 2 < nIter) WRITESET0(0);
        COMPUTE(1);
        LGKM_BARRIER();
    }

#undef LOADSET0
#undef LOADSET1
#undef WRITESET0
#undef WRITESET1
#undef COMPUTE

    // epilogue: D row = lq*4 + r, col = l15  (verified m89 C/D layout)
    float* Pf = Cf + (size_t)z * M * N;
    for (int mt = 0; mt < 4; ++mt)
        for (int nt = 0; nt < 4; ++nt)
            for (int r = 0; r < 4; ++r) {
                const int row = m0 + wm + mt * 16 + lq * 4 + r;
                const int col = n0 + wn + nt * 16 + l15;
                if (EPI == 0) {
                    const float v = acc[mt][nt][r] + bias[col];
                    Cb[(size_t)row * N + col] = __float2bfloat16(v);
                } else if (EPI == 2) {
                    const float v = acc[mt][nt][r] + bias[col];
                    const float g = 0.5f * v * (1.0f + erff(v * 0.70710678118654752f));
                    Cb[(size_t)row * N + col] = __float2bfloat16(g);
                } else {
                    Pf[(size_t)row * N + col] = acc[mt][nt][r];
                }
            }
}

// ---------------------------------------------------------------------------
// split-K=2 reduce: out = P0 + P1 + bias + res   (float4 vectorized)
// ---------------------------------------------------------------------------
__global__ __launch_bounds__(256) void reduce2(
    const float* __restrict__ P, const float* __restrict__ bias,
    const float* __restrict__ res, float* __restrict__ out, int MN, int N)
{
    const int i = (blockIdx.x * 256 + threadIdx.x) * 4;
    if (i >= MN) return;
    const float4 p0 = *(const float4*)(P + i);
    const float4 p1 = *(const float4*)(P + MN + i);
    const float4 r  = *(const float4*)(res + i);
    const float4 b  = *(const float4*)(bias + (i % N));
    float4 o;
    o.x = p0.x + p1.x + r.x + b.x;
    o.y = p0.y + p1.y + r.y + b.y;
    o.z = p0.z + p1.z + r.z + b.z;
    o.w = p0.w + p1.w + r.w + b.w;
    *(float4*)(out + i) = o;
}

// ---------------------------------------------------------------------------
// Flash attention v3 (unchanged from round 6): transposed-S formulation.
// ---------------------------------------------------------------------------
__global__ __launch_bounds__(256) void flash_attn(
    const bf16* __restrict__ qb, const bf16* __restrict__ kb,
    const bf16* __restrict__ vb, bf16* __restrict__ ob, int ldq)
{
    __shared__ bf16 Ks[2][64][64];    // 16 KB  [kv][d]
    __shared__ bf16 Vt[64][64];       // 8 KB   [d][kv]
    __shared__ bf16 Ps[4][16][64];    // 8 KB   per-wave P^T as [q][kv]

    const int bh = blockIdx.y;
    const int b  = bh / NHEAD;
    const int hh = bh % NHEAD;
    const int q0 = blockIdx.x * 64;
    const int tid  = threadIdx.x;
    const int lane = tid & 63;
    const int wid  = tid >> 6;
    const int l15  = lane & 15;
    const int lq   = lane >> 4;
    const int key  = l15 & 7;

    short8 qf[2];
    {
        const bf16* qp = qb + (size_t)(b * SEQ + q0 + wid * 16 + l15) * ldq
                         + hh * HDIM + lq * 8;
        for (int kk = 0; kk < 2; ++kk) {
            union { short8 v; bf16 h[8]; } u;
            u.v = *(const short8*)(qp + kk * 32);
            for (int j = 0; j < 8; ++j)
                u.h[j] = __float2bfloat16(__bfloat162float(u.h[j]) * 0.125f);
            qf[kk] = u.v;
        }
    }

    f32x4 o[4];   // O^T: row d = dt*16 + lq*4 + r, col q = l15
    for (int dt = 0; dt < 4; ++dt) o[dt] = (f32x4){0.f, 0.f, 0.f, 0.f};
    float lsum = 0.f;

    const int krow  = wid * 8 + (lane >> 3);
    const int kcgl8 = ((lane & 7) ^ (krow & 7)) * 8;
    const int kcph8 = (lane & 7) * 8;
    const int vd0  = (tid & 15) * 4;
    const int vkv0 = (tid >> 4) * 4;

    const bf16* kBase = kb + (size_t)(b * SEQ + krow) * ldq + hh * HDIM + kcgl8;
    const bf16* vBase = vb + (size_t)(b * SEQ + vkv0) * ldq + hh * HDIM + vd0;

    GLDS(kBase,                    &Ks[0][krow][kcph8]);
    GLDS(kBase + (size_t)32 * ldq, &Ks[0][krow + 32][kcph8]);
    u16x4 vr[4];
    for (int j = 0; j < 4; ++j)
        vr[j] = *(const u16x4*)(vBase + (size_t)j * ldq);

    const int nIter = SEQ / 64;
    for (int it = 0; it < nIter; ++it) {
        const int buf = it & 1;
        __syncthreads();   // Ks[buf] landed (vmcnt drain); prior Vt reads done
        for (int i = 0; i < 4; ++i) {
            u16x4 w = { vr[0][i], vr[1][i], vr[2][i], vr[3][i] };
            const int p = ((vkv0 >> 3) ^ ((vd0 + i) & 7)) * 8 + (vkv0 & 7);
            *(u16x4*)(&Vt[vd0 + i][p]) = w;
        }
        __syncthreads();   // Vt published

        if (it + 1 < nIter) {
            const size_t off = (size_t)(it + 1) * 64 * ldq;
            GLDS(kBase + off,                    &Ks[buf ^ 1][krow][kcph8]);
            GLDS(kBase + off + (size_t)32 * ldq, &Ks[buf ^ 1][krow + 32][kcph8]);
            for (int j = 0; j < 4; ++j)
                vr[j] = *(const u16x4*)(vBase + off + (size_t)j * ldq);
        }

        // ---- S^T = K Q^T ----
        for (int mt = 0; mt < 4; ++mt) {
            const bf16* kp = &Ks[buf][mt * 16 + l15][0];
            const short8 kf0 = *(const short8*)(kp + ((0 + lq) ^ key) * 8);
            const short8 kf1 = *(const short8*)(kp + ((4 + lq) ^ key) * 8);
            f32x4 a = (f32x4){0.f, 0.f, 0.f, 0.f};
            a = __builtin_amdgcn_mfma_f32_16x16x32_bf16(kf0, qf[0], a, 0, 0, 0);
            a = __builtin_amdgcn_mfma_f32_16x16x32_bf16(kf1, qf[1], a, 0, 0, 0);
            union { u16x4 v; bf16 h[4]; } pk;
            for (int r = 0; r < 4; ++r) {
                const float p = __expf(a[r]);
                lsum += p;
                pk.h[r] = __float2bfloat16(p);
            }
            const int pc = ((mt * 2 + (lq >> 1)) ^ key) * 8 + (lq & 1) * 4;
            *(u16x4*)(&Ps[wid][l15][pc]) = pk.v;
        }

        // ---- O^T += V^T P^T ----
        for (int kk = 0; kk < 2; ++kk) {
            const short8 pf = *(const short8*)(
                &Ps[wid][l15][((lq + 4 * kk) ^ key) * 8]);
            for (int dt = 0; dt < 4; ++dt) {
                const short8 vf = *(const short8*)(
                    &Vt[dt * 16 + l15][((lq + 4 * kk) ^ key) * 8]);
                o[dt] = __builtin_amdgcn_mfma_f32_16x16x32_bf16(
                    vf, pf, o[dt], 0, 0, 0);
            }
        }
    }

    lsum += __shfl_xor(lsum, 16);
    lsum += __shfl_xor(lsum, 32);
    const float inv_l = 1.0f / lsum;

    const size_t qrow = (size_t)(b * SEQ + q0 + wid * 16 + l15);
    for (int dt = 0; dt < 4; ++dt) {
        union { u16x4 v; bf16 h[4]; } w;
        for (int r = 0; r < 4; ++r)
            w.h[r] = __float2bfloat16(o[dt][r] * inv_l);
        *(u16x4*)(ob + qrow * DMODEL + hh * HDIM + dt * 16 + lq * 4) = w.v;
    }
}

// ---------------------------------------------------------------------------
extern "C" void kernel_launch(void* const* d_in, const int* in_sizes, int n_in,
                              void* d_out, int out_size, void* d_ws, size_t ws_size,
                              hipStream_t stream)
{
    (void)in_sizes; (void)n_in; (void)out_size; (void)ws_size;
    const float* x    = (const float*)d_in[0];
    const float* ln1s = (const float*)d_in[1];
    const float* ln1o = (const float*)d_in[2];
    const float* wq   = (const float*)d_in[3];
    const float* bq   = (const float*)d_in[4];
    const float* wk   = (const float*)d_in[5];
    const float* bk   = (const float*)d_in[6];
    const float* wv   = (const float*)d_in[7];
    const float* bv   = (const float*)d_in[8];
    const float* wo   = (const float*)d_in[9];
    const float* bo   = (const float*)d_in[10];
    const float* ln2s = (const float*)d_in[11];
    const float* ln2o = (const float*)d_in[12];
    const float* fc1w = (const float*)d_in[13];
    const float* fc1b = (const float*)d_in[14];
    const float* fc2w = (const float*)d_in[15];
    const float* fc2b = (const float*)d_in[16];
    float* out = (float*)d_out;

    char* wp = (char*)d_ws;
    auto alloc = [&](size_t n) { char* p = wp; wp += (n + 255) & ~(size_t)255; return p; };
    bf16*  wqkvt = (bf16*)alloc((size_t)3 * DMODEL * DMODEL * 2);
    bf16*  wot   = (bf16*)alloc((size_t)DMODEL * DMODEL * 2);
    bf16*  fc1t  = (bf16*)alloc((size_t)DFFN * DMODEL * 2);    // [5120][1280]
    bf16*  fc2t  = (bf16*)alloc((size_t)DMODEL * DFFN * 2);    // [1280][5120]
    float* bqkv  = (float*)alloc((size_t)3 * DMODEL * 4);
    // region A: h | qkv | attn ; partials (split-K=2, 41.94 MB) alias h+qkv
    char*  regA  = alloc((size_t)NROWS * DMODEL * 2      // h
                       + (size_t)NROWS * 3 * DMODEL * 2  // qkv
                       + (size_t)NROWS * DMODEL * 2);    // attn
    bf16*  h     = (bf16*)regA;
    bf16*  qkv   = (bf16*)(regA + (size_t)NROWS * DMODEL * 2);
    bf16*  attn  = (bf16*)(regA + (size_t)NROWS * 4 * DMODEL * 2);
    float* part  = (float*)regA;                         // 2 * NROWS*DMODEL f32
    bf16*  h2    = (bf16*)alloc((size_t)NROWS * DMODEL * 2);
    bf16*  g     = (bf16*)alloc((size_t)NROWS * DFFN * 2);
    float* x1    = out;   // post-attention residual lives in d_out

    const dim3 tb(32, 8);
    transpose_cvt4<<<dim3(DMODEL / 32, DMODEL / 32, 4), tb, 0, stream>>>(
        wq, wk, wv, wo,
        wqkvt, wqkvt + (size_t)DMODEL * DMODEL, wqkvt + (size_t)2 * DMODEL * DMODEL, wot);
    transpose_cvt<<<dim3(DFFN / 32, DMODEL / 32), tb, 0, stream>>>(fc1w, fc1t, DMODEL, DFFN);
    transpose_cvt<<<dim3(DMODEL / 32, DFFN / 32), tb, 0, stream>>>(fc2w, fc2t, DFFN, DMODEL);
    pack_bias3<<<(DMODEL + 255) / 256, 256, 0, stream>>>(bq, bk, bv, bqkv);

    ln_bf16<<<NROWS, 256, 0, stream>>>(x, ln1s, ln1o, h);

    // fused QKV: [4096,1280] @ [1280,3840] -> qkv [4096,3840]  (m-tile fastest)
    gemm_bf16<0><<<dim3(NROWS / 128, 3 * DMODEL / 128, 1), 256, 0, stream>>>(
        h, wqkvt, bqkv, qkv, nullptr, NROWS, 3 * DMODEL, DMODEL, DMODEL);

    flash_attn<<<dim3(SEQ / 64, BATCH * NHEAD), 256, 0, stream>>>(
        qkv, qkv + DMODEL, qkv + 2 * DMODEL, attn, 3 * DMODEL);

    // WO split-K=2 -> partials, then fused reduce(+bo+x)+LN2 -> x1, h2
    gemm_bf16<3><<<dim3(NROWS / 128, DMODEL / 128, 2), 256, 0, stream>>>(
        attn, wot, nullptr, nullptr, part, NROWS, DMODEL, DMODEL, DMODEL / 2);
    reduce2_ln<<<NROWS, 256, 0, stream>>>(part, bo, x, x1, ln2s, ln2o, h2);

    // FC1 + exact GELU
    gemm_bf16<2><<<dim3(NROWS / 128, DFFN / 128, 1), 256, 0, stream>>>(
        h2, fc1t, fc1b, g, nullptr, NROWS, DFFN, DMODEL, DMODEL);

    // FC2 split-K=2 -> partials, then reduce(+fc2b+x1) -> out (in place)
    gemm_bf16<3><<<dim3(NROWS / 128, DMODEL / 128, 2), 256, 0, stream>>>(
        g, fc2t, nullptr, nullptr, part, NROWS, DMODEL, DFFN, DFFN / 2);
    reduce2<<<(NROWS * DMODEL / 4 + 255) / 256, 256, 0, stream>>>(
        part, fc2b, x1, out, NROWS * DMODEL, DMODEL);
}

// Round 8
// 473.875 us; speedup vs baseline: 1.0712x; 1.0712x over previous
//
#include <hip/hip_runtime.h>
#include <hip/hip_bf16.h>

typedef __hip_bfloat16 bf16;
typedef __attribute__((ext_vector_type(8))) short short8;
typedef __attribute__((ext_vector_type(4))) float f32x4;
typedef __attribute__((ext_vector_type(4))) unsigned short u16x4;

#define DMODEL 1280
#define DFFN   5120
#define BATCH  4
#define SEQ    1024
#define NHEAD  20
#define HDIM   64
#define NROWS  (BATCH * SEQ)   // 4096

// async global->LDS, 16B per lane; HW dest = wave-uniform base + lane*16
#define GLDS(g, l) __builtin_amdgcn_global_load_lds(                            \
    (const __attribute__((address_space(1))) void*)(g),                         \
    (__attribute__((address_space(3))) void*)(l), 16, 0, 0)

// ---------------------------------------------------------------------------
// Unified prep: 6 weight transposes (fp32 [K,N] -> bf16 [N,K]) + bias pack,
// one dispatch. Flat grid decode:
//   [0,6400)      : 4 square DMODEL^2 transposes (1600 tiles each)
//   [6400,12800)  : fc1 (K=DMODEL, N=DFFN)   160 x 40 tiles
//   [12800,19200) : fc2 (K=DFFN, N=DMODEL)   40 x 160 tiles
//   19200         : pack bq|bk|bv
// ---------------------------------------------------------------------------
__global__ __launch_bounds__(256) void prep_all(
    const float* __restrict__ wq, const float* __restrict__ wk,
    const float* __restrict__ wv, const float* __restrict__ wo,
    const float* __restrict__ fc1w, const float* __restrict__ fc2w,
    const float* __restrict__ bq, const float* __restrict__ bk,
    const float* __restrict__ bv,
    bf16* __restrict__ wqkvt, bf16* __restrict__ wot,
    bf16* __restrict__ fc1t, bf16* __restrict__ fc2t,
    float* __restrict__ bqkv)
{
    const int bid = blockIdx.x;
    if (bid == 19200) {
        for (int i = threadIdx.x; i < DMODEL; i += 256) {
            bqkv[i]              = bq[i];
            bqkv[DMODEL + i]     = bk[i];
            bqkv[2 * DMODEL + i] = bv[i];
        }
        return;
    }
    const float* in;
    bf16* out;
    int K, N, n0, k0;
    if (bid < 6400) {
        const int mat = bid / 1600, rem = bid % 1600;
        K = DMODEL; N = DMODEL;
        n0 = (rem % 40) * 32; k0 = (rem / 40) * 32;
        switch (mat) {
            case 0:  in = wq; out = wqkvt; break;
            case 1:  in = wk; out = wqkvt + (size_t)DMODEL * DMODEL; break;
            case 2:  in = wv; out = wqkvt + (size_t)2 * DMODEL * DMODEL; break;
            default: in = wo; out = wot; break;
        }
    } else if (bid < 12800) {
        const int rem = bid - 6400;
        K = DMODEL; N = DFFN; in = fc1w; out = fc1t;
        n0 = (rem % 160) * 32; k0 = (rem / 160) * 32;
    } else {
        const int rem = bid - 12800;
        K = DFFN; N = DMODEL; in = fc2w; out = fc2t;
        n0 = (rem % 40) * 32; k0 = (rem / 40) * 32;
    }
    __shared__ float tile[32][33];
    const int tx = threadIdx.x & 31;
    const int ty = threadIdx.x >> 5;   // 0..7
    for (int i = 0; i < 32; i += 8)
        tile[ty + i][tx] = in[(size_t)(k0 + ty + i) * N + (n0 + tx)];
    __syncthreads();
    for (int i = 0; i < 32; i += 8)
        out[(size_t)(n0 + ty + i) * K + (k0 + tx)] = __float2bfloat16(tile[tx][ty + i]);
}

// ---------------------------------------------------------------------------
// LayerNorm over last dim (1280), one block (256 thr) per row, bf16 out
// ---------------------------------------------------------------------------
__global__ __launch_bounds__(256) void ln_bf16(
    const float* __restrict__ x, const float* __restrict__ sc,
    const float* __restrict__ of, bf16* __restrict__ out)
{
    const int row = blockIdx.x;
    const float* xr = x + (size_t)row * DMODEL;
    float v[5];
    float s = 0.f, s2 = 0.f;
    for (int i = 0; i < 5; ++i) {
        v[i] = xr[threadIdx.x + i * 256];
        s += v[i];
        s2 += v[i] * v[i];
    }
    for (int off = 1; off < 64; off <<= 1) {
        s  += __shfl_xor(s, off);
        s2 += __shfl_xor(s2, off);
    }
    __shared__ float red[2][4];
    const int wid = threadIdx.x >> 6;
    if ((threadIdx.x & 63) == 0) { red[0][wid] = s; red[1][wid] = s2; }
    __syncthreads();
    s  = red[0][0] + red[0][1] + red[0][2] + red[0][3];
    s2 = red[1][0] + red[1][1] + red[1][2] + red[1][3];
    const float mean = s * (1.0f / DMODEL);
    const float var  = s2 * (1.0f / DMODEL) - mean * mean;
    const float rstd = rsqrtf(var + 1e-5f);
    for (int i = 0; i < 5; ++i) {
        const int c = threadIdx.x + i * 256;
        const float y = (v[i] - mean) * rstd * sc[c] + of[c];
        out[(size_t)row * DMODEL + c] = __float2bfloat16(y);
    }
}

// ---------------------------------------------------------------------------
// Fused: x1 = P0 + P1 + bias + res;  h2 = LayerNorm(x1)*sc + of  (bf16)
// ---------------------------------------------------------------------------
__global__ __launch_bounds__(256) void reduce2_ln(
    const float* __restrict__ P, const float* __restrict__ bias,
    const float* __restrict__ res, float* __restrict__ x1,
    const float* __restrict__ sc, const float* __restrict__ of,
    bf16* __restrict__ h2)
{
    const int row = blockIdx.x;
    const size_t base = (size_t)row * DMODEL;
    const int MN = NROWS * DMODEL;
    float v[5];
    float s = 0.f, s2 = 0.f;
    for (int i = 0; i < 5; ++i) {
        const int c = threadIdx.x + i * 256;
        const float val = P[base + c] + P[MN + base + c] + bias[c] + res[base + c];
        v[i] = val;
        x1[base + c] = val;
        s += val;
        s2 += val * val;
    }
    for (int off = 1; off < 64; off <<= 1) {
        s  += __shfl_xor(s, off);
        s2 += __shfl_xor(s2, off);
    }
    __shared__ float red[2][4];
    const int wid = threadIdx.x >> 6;
    if ((threadIdx.x & 63) == 0) { red[0][wid] = s; red[1][wid] = s2; }
    __syncthreads();
    s  = red[0][0] + red[0][1] + red[0][2] + red[0][3];
    s2 = red[1][0] + red[1][1] + red[1][2] + red[1][3];
    const float mean = s * (1.0f / DMODEL);
    const float var  = s2 * (1.0f / DMODEL) - mean * mean;
    const float rstd = rsqrtf(var + 1e-5f);
    for (int i = 0; i < 5; ++i) {
        const int c = threadIdx.x + i * 256;
        const float y = (v[i] - mean) * rstd * sc[c] + of[c];
        h2[base + c] = __float2bfloat16(y);
    }
}

// ---------------------------------------------------------------------------
// bf16 MFMA GEMM v5 = round-6 v3 structure + round-7 conflict-free swizzle.
//  - BK=32 double-buffered GLDS, ONE barrier/iter, prefetch after barrier.
//  - launch_bounds(256,4): VGPR 52, ~4 blocks/CU (best measured occupancy).
//  - swizzle key (row>>1)&3 on the GLOBAL source chunk; GLDS HW write is a
//    contiguous 1KB DMA (conflict-free); ds_read_b128 with matching key
//    measured 0 conflicts (round 7).
//  - m-tile = blockIdx.x fastest (XCD/L2 locality; FETCH 204->62MB, round 3).
// EPI 0: bf16 out = acc + bias
// EPI 2: bf16 out = gelu_exact(acc + bias)
// EPI 3: f32 partial[z] = acc  (split-K via blockIdx.z)
// ---------------------------------------------------------------------------
template <int EPI>
__global__ __launch_bounds__(256, 4) void gemm_bf16(
    const bf16* __restrict__ A, const bf16* __restrict__ Bt,
    const float* __restrict__ bias,
    bf16* __restrict__ Cb, float* __restrict__ Cf,
    int M, int N, int K, int klen)
{
    __shared__ bf16 As[2][128][32];   // 16 KB
    __shared__ bf16 Bs[2][128][32];   // 16 KB
    const int m0 = blockIdx.x * 128;
    const int n0 = blockIdx.y * 128;
    const int z  = blockIdx.z;
    const int kbeg = z * klen;

    const int tid  = threadIdx.x;
    const int lane = tid & 63;
    const int wid  = tid >> 6;
    const int wm   = (wid >> 1) * 64;
    const int wn   = (wid & 1) * 64;
    const int l15  = lane & 15;
    const int lq   = lane >> 4;

    f32x4 acc[4][4];
    for (int i = 0; i < 4; ++i)
        for (int j = 0; j < 4; ++j)
            acc[i][j] = (f32x4){0.f, 0.f, 0.f, 0.f};

    // staging: wave covers 16 rows x 64B per GLDS; 2 GLDS per matrix per iter
    const int srow = lane >> 2;                          // 0..15
    const int cph  = lane & 3;                           // physical 16B chunk
    const int cgl8 = (cph ^ ((srow >> 1) & 3)) * 8;      // swizzled global chunk
    const int lrow = wid * 16 + srow;
    const int lcol = cph * 8;

    const bf16* aT = A  + (size_t)(m0 + lrow) * K + kbeg + cgl8;
    const bf16* bT = Bt + (size_t)(n0 + lrow) * K + kbeg + cgl8;
    const size_t rstep = (size_t)64 * K;

    // prologue: tile 0 -> buf 0
    GLDS(aT,         &As[0][lrow][lcol]);
    GLDS(aT + rstep, &As[0][lrow + 64][lcol]);
    GLDS(bT,         &Bs[0][lrow][lcol]);
    GLDS(bT + rstep, &Bs[0][lrow + 64][lcol]);

    const int ca = (lq ^ ((l15 >> 1) & 3)) * 8;   // conflict-free frag chunk
    const int nIter = klen / 32;
    for (int it = 0; it < nIter; ++it) {
        const int buf = it & 1;
        __syncthreads();   // drains vmcnt: tile `it` visible; prior reads done
        if (it + 1 < nIter) {
            const int k1 = (it + 1) * 32;
            GLDS(aT + k1,         &As[buf ^ 1][lrow][lcol]);
            GLDS(aT + k1 + rstep, &As[buf ^ 1][lrow + 64][lcol]);
            GLDS(bT + k1,         &Bs[buf ^ 1][lrow][lcol]);
            GLDS(bT + k1 + rstep, &Bs[buf ^ 1][lrow + 64][lcol]);
        }
        short8 af[4], bfr[4];
        for (int mt = 0; mt < 4; ++mt)
            af[mt] = *(const short8*)(&As[buf][wm + mt * 16 + l15][ca]);
        for (int nt = 0; nt < 4; ++nt)
            bfr[nt] = *(const short8*)(&Bs[buf][wn + nt * 16 + l15][ca]);
        for (int mt = 0; mt < 4; ++mt)
            for (int nt = 0; nt < 4; ++nt)
                acc[mt][nt] = __builtin_amdgcn_mfma_f32_16x16x32_bf16(
                    af[mt], bfr[nt], acc[mt][nt], 0, 0, 0);
    }

    // epilogue: D row = lq*4 + r, col = l15  (verified m89 C/D layout)
    float* Pf = Cf + (size_t)z * M * N;
    for (int mt = 0; mt < 4; ++mt)
        for (int nt = 0; nt < 4; ++nt)
            for (int r = 0; r < 4; ++r) {
                const int row = m0 + wm + mt * 16 + lq * 4 + r;
                const int col = n0 + wn + nt * 16 + l15;
                if (EPI == 0) {
                    const float v = acc[mt][nt][r] + bias[col];
                    Cb[(size_t)row * N + col] = __float2bfloat16(v);
                } else if (EPI == 2) {
                    const float v = acc[mt][nt][r] + bias[col];
                    const float g = 0.5f * v * (1.0f + erff(v * 0.70710678118654752f));
                    Cb[(size_t)row * N + col] = __float2bfloat16(g);
                } else {
                    Pf[(size_t)row * N + col] = acc[mt][nt][r];
                }
            }
}

// ---------------------------------------------------------------------------
// split-K=2 reduce: out = P0 + P1 + bias + res   (float4 vectorized)
// ---------------------------------------------------------------------------
__global__ __launch_bounds__(256) void reduce2(
    const float* __restrict__ P, const float* __restrict__ bias,
    const float* __restrict__ res, float* __restrict__ out, int MN, int N)
{
    const int i = (blockIdx.x * 256 + threadIdx.x) * 4;
    if (i >= MN) return;
    const float4 p0 = *(const float4*)(P + i);
    const float4 p1 = *(const float4*)(P + MN + i);
    const float4 r  = *(const float4*)(res + i);
    const float4 b  = *(const float4*)(bias + (i % N));
    float4 o;
    o.x = p0.x + p1.x + r.x + b.x;
    o.y = p0.y + p1.y + r.y + b.y;
    o.z = p0.z + p1.z + r.z + b.z;
    o.w = p0.w + p1.w + r.w + b.w;
    *(float4*)(out + i) = o;
}

// ---------------------------------------------------------------------------
// Flash attention v3 (unchanged from round 6): transposed-S formulation.
// ---------------------------------------------------------------------------
__global__ __launch_bounds__(256) void flash_attn(
    const bf16* __restrict__ qb, const bf16* __restrict__ kb,
    const bf16* __restrict__ vb, bf16* __restrict__ ob, int ldq)
{
    __shared__ bf16 Ks[2][64][64];    // 16 KB  [kv][d]
    __shared__ bf16 Vt[64][64];       // 8 KB   [d][kv]
    __shared__ bf16 Ps[4][16][64];    // 8 KB   per-wave P^T as [q][kv]

    const int bh = blockIdx.y;
    const int b  = bh / NHEAD;
    const int hh = bh % NHEAD;
    const int q0 = blockIdx.x * 64;
    const int tid  = threadIdx.x;
    const int lane = tid & 63;
    const int wid  = tid >> 6;
    const int l15  = lane & 15;
    const int lq   = lane >> 4;
    const int key  = l15 & 7;

    short8 qf[2];
    {
        const bf16* qp = qb + (size_t)(b * SEQ + q0 + wid * 16 + l15) * ldq
                         + hh * HDIM + lq * 8;
        for (int kk = 0; kk < 2; ++kk) {
            union { short8 v; bf16 h[8]; } u;
            u.v = *(const short8*)(qp + kk * 32);
            for (int j = 0; j < 8; ++j)
                u.h[j] = __float2bfloat16(__bfloat162float(u.h[j]) * 0.125f);
            qf[kk] = u.v;
        }
    }

    f32x4 o[4];   // O^T: row d = dt*16 + lq*4 + r, col q = l15
    for (int dt = 0; dt < 4; ++dt) o[dt] = (f32x4){0.f, 0.f, 0.f, 0.f};
    float lsum = 0.f;

    const int krow  = wid * 8 + (lane >> 3);
    const int kcgl8 = ((lane & 7) ^ (krow & 7)) * 8;
    const int kcph8 = (lane & 7) * 8;
    const int vd0  = (tid & 15) * 4;
    const int vkv0 = (tid >> 4) * 4;

    const bf16* kBase = kb + (size_t)(b * SEQ + krow) * ldq + hh * HDIM + kcgl8;
    const bf16* vBase = vb + (size_t)(b * SEQ + vkv0) * ldq + hh * HDIM + vd0;

    GLDS(kBase,                    &Ks[0][krow][kcph8]);
    GLDS(kBase + (size_t)32 * ldq, &Ks[0][krow + 32][kcph8]);
    u16x4 vr[4];
    for (int j = 0; j < 4; ++j)
        vr[j] = *(const u16x4*)(vBase + (size_t)j * ldq);

    const int nIter = SEQ / 64;
    for (int it = 0; it < nIter; ++it) {
        const int buf = it & 1;
        __syncthreads();   // Ks[buf] landed (vmcnt drain); prior Vt reads done
        for (int i = 0; i < 4; ++i) {
            u16x4 w = { vr[0][i], vr[1][i], vr[2][i], vr[3][i] };
            const int p = ((vkv0 >> 3) ^ ((vd0 + i) & 7)) * 8 + (vkv0 & 7);
            *(u16x4*)(&Vt[vd0 + i][p]) = w;
        }
        __syncthreads();   // Vt published

        if (it + 1 < nIter) {
            const size_t off = (size_t)(it + 1) * 64 * ldq;
            GLDS(kBase + off,                    &Ks[buf ^ 1][krow][kcph8]);
            GLDS(kBase + off + (size_t)32 * ldq, &Ks[buf ^ 1][krow + 32][kcph8]);
            for (int j = 0; j < 4; ++j)
                vr[j] = *(const u16x4*)(vBase + off + (size_t)j * ldq);
        }

        // ---- S^T = K Q^T ----
        for (int mt = 0; mt < 4; ++mt) {
            const bf16* kp = &Ks[buf][mt * 16 + l15][0];
            const short8 kf0 = *(const short8*)(kp + ((0 + lq) ^ key) * 8);
            const short8 kf1 = *(const short8*)(kp + ((4 + lq) ^ key) * 8);
            f32x4 a = (f32x4){0.f, 0.f, 0.f, 0.f};
            a = __builtin_amdgcn_mfma_f32_16x16x32_bf16(kf0, qf[0], a, 0, 0, 0);
            a = __builtin_amdgcn_mfma_f32_16x16x32_bf16(kf1, qf[1], a, 0, 0, 0);
            union { u16x4 v; bf16 h[4]; } pk;
            for (int r = 0; r < 4; ++r) {
                const float p = __expf(a[r]);
                lsum += p;
                pk.h[r] = __float2bfloat16(p);
            }
            const int pc = ((mt * 2 + (lq >> 1)) ^ key) * 8 + (lq & 1) * 4;
            *(u16x4*)(&Ps[wid][l15][pc]) = pk.v;
        }

        // ---- O^T += V^T P^T ----
        for (int kk = 0; kk < 2; ++kk) {
            const short8 pf = *(const short8*)(
                &Ps[wid][l15][((lq + 4 * kk) ^ key) * 8]);
            for (int dt = 0; dt < 4; ++dt) {
                const short8 vf = *(const short8*)(
                    &Vt[dt * 16 + l15][((lq + 4 * kk) ^ key) * 8]);
                o[dt] = __builtin_amdgcn_mfma_f32_16x16x32_bf16(
                    vf, pf, o[dt], 0, 0, 0);
            }
        }
    }

    lsum += __shfl_xor(lsum, 16);
    lsum += __shfl_xor(lsum, 32);
    const float inv_l = 1.0f / lsum;

    const size_t qrow = (size_t)(b * SEQ + q0 + wid * 16 + l15);
    for (int dt = 0; dt < 4; ++dt) {
        union { u16x4 v; bf16 h[4]; } w;
        for (int r = 0; r < 4; ++r)
            w.h[r] = __float2bfloat16(o[dt][r] * inv_l);
        *(u16x4*)(ob + qrow * DMODEL + hh * HDIM + dt * 16 + lq * 4) = w.v;
    }
}

// ---------------------------------------------------------------------------
extern "C" void kernel_launch(void* const* d_in, const int* in_sizes, int n_in,
                              void* d_out, int out_size, void* d_ws, size_t ws_size,
                              hipStream_t stream)
{
    (void)in_sizes; (void)n_in; (void)out_size; (void)ws_size;
    const float* x    = (const float*)d_in[0];
    const float* ln1s = (const float*)d_in[1];
    const float* ln1o = (const float*)d_in[2];
    const float* wq   = (const float*)d_in[3];
    const float* bq   = (const float*)d_in[4];
    const float* wk   = (const float*)d_in[5];
    const float* bk   = (const float*)d_in[6];
    const float* wv   = (const float*)d_in[7];
    const float* bv   = (const float*)d_in[8];
    const float* wo   = (const float*)d_in[9];
    const float* bo   = (const float*)d_in[10];
    const float* ln2s = (const float*)d_in[11];
    const float* ln2o = (const float*)d_in[12];
    const float* fc1w = (const float*)d_in[13];
    const float* fc1b = (const float*)d_in[14];
    const float* fc2w = (const float*)d_in[15];
    const float* fc2b = (const float*)d_in[16];
    float* out = (float*)d_out;

    char* wp = (char*)d_ws;
    auto alloc = [&](size_t n) { char* p = wp; wp += (n + 255) & ~(size_t)255; return p; };
    bf16*  wqkvt = (bf16*)alloc((size_t)3 * DMODEL * DMODEL * 2);
    bf16*  wot   = (bf16*)alloc((size_t)DMODEL * DMODEL * 2);
    bf16*  fc1t  = (bf16*)alloc((size_t)DFFN * DMODEL * 2);    // [5120][1280]
    bf16*  fc2t  = (bf16*)alloc((size_t)DMODEL * DFFN * 2);    // [1280][5120]
    float* bqkv  = (float*)alloc((size_t)3 * DMODEL * 4);
    // region A: h | qkv | attn ; partials (split-K=2, 41.94 MB) alias h+qkv
    char*  regA  = alloc((size_t)NROWS * DMODEL * 2      // h
                       + (size_t)NROWS * 3 * DMODEL * 2  // qkv
                       + (size_t)NROWS * DMODEL * 2);    // attn
    bf16*  h     = (bf16*)regA;
    bf16*  qkv   = (bf16*)(regA + (size_t)NROWS * DMODEL * 2);
    bf16*  attn  = (bf16*)(regA + (size_t)NROWS * 4 * DMODEL * 2);
    float* part  = (float*)regA;                         // 2 * NROWS*DMODEL f32
    bf16*  h2    = (bf16*)alloc((size_t)NROWS * DMODEL * 2);
    bf16*  g     = (bf16*)alloc((size_t)NROWS * DFFN * 2);
    float* x1    = out;   // post-attention residual lives in d_out

    prep_all<<<19201, 256, 0, stream>>>(
        wq, wk, wv, wo, fc1w, fc2w, bq, bk, bv,
        wqkvt, wot, fc1t, fc2t, bqkv);

    ln_bf16<<<NROWS, 256, 0, stream>>>(x, ln1s, ln1o, h);

    // fused QKV: [4096,1280] @ [1280,3840] -> qkv [4096,3840]  (m-tile fastest)
    gemm_bf16<0><<<dim3(NROWS / 128, 3 * DMODEL / 128, 1), 256, 0, stream>>>(
        h, wqkvt, bqkv, qkv, nullptr, NROWS, 3 * DMODEL, DMODEL, DMODEL);

    flash_attn<<<dim3(SEQ / 64, BATCH * NHEAD), 256, 0, stream>>>(
        qkv, qkv + DMODEL, qkv + 2 * DMODEL, attn, 3 * DMODEL);

    // WO split-K=2 -> partials, then fused reduce(+bo+x)+LN2 -> x1, h2
    gemm_bf16<3><<<dim3(NROWS / 128, DMODEL / 128, 2), 256, 0, stream>>>(
        attn, wot, nullptr, nullptr, part, NROWS, DMODEL, DMODEL, DMODEL / 2);
    reduce2_ln<<<NROWS, 256, 0, stream>>>(part, bo, x, x1, ln2s, ln2o, h2);

    // FC1 + exact GELU
    gemm_bf16<2><<<dim3(NROWS / 128, DFFN / 128, 1), 256, 0, stream>>>(
        h2, fc1t, fc1b, g, nullptr, NROWS, DFFN, DMODEL, DMODEL);

    // FC2 split-K=2 -> partials, then reduce(+fc2b+x1) -> out (in place)
    gemm_bf16<3><<<dim3(NROWS / 128, DMODEL / 128, 2), 256, 0, stream>>>(
        g, fc2t, nullptr, nullptr, part, NROWS, DMODEL, DFFN, DFFN / 2);
    reduce2<<<(NROWS * DMODEL / 4 + 255) / 256, 256, 0, stream>>>(
        part, fc2b, x1, out, NROWS * DMODEL, DMODEL);
}